// Round 12
// baseline (125.313 us; speedup 1.0000x reference)
//
#include <hip/hip_runtime.h>

#define DROWS 4096
#define NCOLS 8192
#define RTILE 64                 // rows per colminmax tile
#define NTILES (DROWS / RTILE)   // 64 partial tiles
#define RBLOCKS 1024             // persistent rowiter blocks (4 per CU)
#define ROWS_PER_BLOCK (DROWS / RBLOCKS)

// ===================== two-level column min/max ===========================

// Per-column partial min/max over a 64-row tile. grid (8, 64); block 256 thr,
// 4 cols/thread, coalesced float4. No atomics, no init required.
__global__ __launch_bounds__(256) void colminmax_part(const float* __restrict__ x,
                                                      float* __restrict__ pmin,
                                                      float* __restrict__ pmax) {
    int c = blockIdx.x * 1024 + threadIdx.x * 4;
    int r0 = blockIdx.y * RTILE;
    const float* p = x + (size_t)r0 * NCOLS + c;

    float4 mn = *(const float4*)p;
    float4 mx = mn;
#pragma unroll 8
    for (int i = 1; i < RTILE; ++i) {
        float4 v = *(const float4*)(p + (size_t)i * NCOLS);
        mn.x = fminf(mn.x, v.x); mn.y = fminf(mn.y, v.y);
        mn.z = fminf(mn.z, v.z); mn.w = fminf(mn.w, v.w);
        mx.x = fmaxf(mx.x, v.x); mx.y = fmaxf(mx.y, v.y);
        mx.z = fmaxf(mx.z, v.z); mx.w = fmaxf(mx.w, v.w);
    }
    size_t o = (size_t)blockIdx.y * NCOLS + c;
    *(float4*)(pmin + o) = mn;
    *(float4*)(pmax + o) = mx;
}

// Reduce 64 partials per column; emit fmin, safe_range, 1/safe_range.
__global__ __launch_bounds__(256) void finalize_part(const float* __restrict__ pmin,
                                                     const float* __restrict__ pmax,
                                                     float* __restrict__ fmin,
                                                     float* __restrict__ fsr,
                                                     float* __restrict__ finv) {
    int col = blockIdx.x * 256 + threadIdx.x;
    float mn = pmin[col];
    float mx = pmax[col];
#pragma unroll 9
    for (int y = 1; y < NTILES; ++y) {
        mn = fminf(mn, pmin[(size_t)y * NCOLS + col]);
        mx = fmaxf(mx, pmax[(size_t)y * NCOLS + col]);
    }
    float r = mx - mn;
    float sr = (r == 0.0f) ? 1.0f : r;  // sklearn _handle_zeros_in_scale
    fmin[col] = mn;
    fsr[col] = sr;
    finv[col] = 1.0f / sr;
}

// ===================== rowiter ============================================

// One-barrier 4-wave block sum, double-buffered slots (8 floats LDS).
// Consecutive calls alternate slot; a slot's next writer is separated from
// its readers by the intervening call's barrier -> single __syncthreads.
__device__ __forceinline__ float block_sum(float v, float* red, int slot) {
#pragma unroll
    for (int m = 32; m; m >>= 1) v += __shfl_xor(v, m, 64);
    int wid = threadIdx.x >> 6;
    int lane = threadIdx.x & 63;
    if (lane == 0) red[slot * 4 + wid] = v;
    __syncthreads();
    float* r = red + slot * 4;
    return (r[0] + r[1]) + (r[2] + r[3]);
}

// Persistent: 1024 blocks (4/CU), each handles rows b, b+1024, b+2048, b+3072.
// Next row's x is prefetched into v[8] BEFORE the 10-iteration compute, so
// global-load latency and the previous store drain hide under compute.
// a[8]+v[8] = 64 data VGPRs; __launch_bounds__(256,4) caps at 128 (no spill).
__global__ __launch_bounds__(256, 4) void rowiter(const float* __restrict__ x,
                                                  const float* __restrict__ fmin,
                                                  const float* __restrict__ fsr,
                                                  const float* __restrict__ finv,
                                                  float* __restrict__ out) {
    int t = threadIdx.x;
    __shared__ float red[8];

    // prefetch first row
    float4 v[8];
    {
        const float* xr = x + (size_t)blockIdx.x * NCOLS;
#pragma unroll
        for (int k = 0; k < 8; ++k)
            v[k] = *(const float4*)(xr + k * 1024 + t * 4);
    }

    for (int r = 0; r < ROWS_PER_BLOCK; ++r) {
        size_t row = (size_t)blockIdx.x + (size_t)r * RBLOCKS;
        float* outr = out + row * NCOLS;

        // normalize prefetched v -> a, start row sum
        float4 a[8];
        float psum = 0.0f;
#pragma unroll
        for (int k = 0; k < 8; ++k) {
            int c = k * 1024 + t * 4;
            float4 mn = *(const float4*)(fmin + c);
            float4 iv = *(const float4*)(finv + c);
            float4 u;
            u.x = (v[k].x - mn.x) * iv.x;
            u.y = (v[k].y - mn.y) * iv.y;
            u.z = (v[k].z - mn.z) * iv.z;
            u.w = (v[k].w - mn.w) * iv.w;
            a[k] = u;
            psum += (u.x + u.y) + (u.z + u.w);
        }

        // issue next row's loads now; they drain during the 10 iterations
        if (r < ROWS_PER_BLOCK - 1) {
            const float* xn = x + (row + RBLOCKS) * NCOLS;
#pragma unroll
            for (int k = 0; k < 8; ++k)
                v[k] = *(const float4*)(xn + k * 1024 + t * 4);
        }

        float sum = block_sum(psum, red, 0);

        // iterations 0..8 (iteration 9 fused below); 3 VALU/elem
#pragma unroll
        for (int it = 0; it < 9; ++it) {
            float c1 = 1.0f + sum * (1.0f / 8192.0f);  // 1 + mean (exact pow-2)
            float add = (it == 0) ? 0.001f : 0.0f;
            psum = 0.0f;
#pragma unroll
            for (int k = 0; k < 8; ++k) {
                float4 u = a[k];
                u.x = fmaf(u.x, c1 - u.x, add);
                u.y = fmaf(u.y, c1 - u.y, add);
                u.z = fmaf(u.z, c1 - u.z, add);
                u.w = fmaf(u.w, c1 - u.w, add);
                a[k] = u;
                psum += (u.x + u.y) + (u.z + u.w);
            }
            sum = block_sum(psum, red, (it + 1) & 1);
        }

        // iteration 9 fused with denormalize + non-temporal store
        float c1 = 1.0f + sum * (1.0f / 8192.0f);
#pragma unroll
        for (int k = 0; k < 8; ++k) {
            int c = k * 1024 + t * 4;
            float4 mn = *(const float4*)(fmin + c);
            float4 sr = *(const float4*)(fsr + c);
            float4 u = a[k];
            u.x = u.x * (c1 - u.x);
            u.y = u.y * (c1 - u.y);
            u.z = u.z * (c1 - u.z);
            u.w = u.w * (c1 - u.w);
            float* o = outr + c;
            __builtin_nontemporal_store(fmaf(u.x, sr.x, mn.x), o + 0);
            __builtin_nontemporal_store(fmaf(u.y, sr.y, mn.y), o + 1);
            __builtin_nontemporal_store(fmaf(u.z, sr.z, mn.z), o + 2);
            __builtin_nontemporal_store(fmaf(u.w, sr.w, mn.w), o + 3);
        }
    }
}

extern "C" void kernel_launch(void* const* d_in, const int* in_sizes, int n_in,
                              void* d_out, int out_size, void* d_ws, size_t ws_size,
                              hipStream_t stream) {
    const float* x = (const float*)d_in[0];
    float* out = (float*)d_out;

    // ws layout: pmin[64][8192] f32 (2 MiB) | pmax (2 MiB) |
    //            fmin | fsr | finv (32 KiB each)  = 4.09 MiB
    float* pmin = (float*)d_ws;
    float* pmax = pmin + (size_t)NTILES * NCOLS;
    float* fmin = pmax + (size_t)NTILES * NCOLS;
    float* fsr = fmin + NCOLS;
    float* finv = fsr + NCOLS;

    colminmax_part<<<dim3(NCOLS / 1024, NTILES), 256, 0, stream>>>(x, pmin, pmax);
    finalize_part<<<NCOLS / 256, 256, 0, stream>>>(pmin, pmax, fmin, fsr, finv);
    rowiter<<<RBLOCKS, 256, 0, stream>>>(x, fmin, fsr, finv, out);
}

// Round 13
// 76.254 us; speedup vs baseline: 1.6434x; 1.6434x over previous
//
#include <hip/hip_runtime.h>

#define DROWS 4096
#define NCOLS 8192
#define RTILE 64                 // rows per colminmax tile
#define NTILES (DROWS / RTILE)   // 64 partial tiles

// ===================== two-level column min/max ===========================

// Per-column partial min/max over a 64-row tile. grid (8, 64); block 256 thr,
// 4 cols/thread, coalesced float4. No atomics, no init required.
__global__ __launch_bounds__(256) void colminmax_part(const float* __restrict__ x,
                                                      float* __restrict__ pmin,
                                                      float* __restrict__ pmax) {
    int c = blockIdx.x * 1024 + threadIdx.x * 4;
    int r0 = blockIdx.y * RTILE;
    const float* p = x + (size_t)r0 * NCOLS + c;

    float4 mn = *(const float4*)p;
    float4 mx = mn;
#pragma unroll 8
    for (int i = 1; i < RTILE; ++i) {
        float4 v = *(const float4*)(p + (size_t)i * NCOLS);
        mn.x = fminf(mn.x, v.x); mn.y = fminf(mn.y, v.y);
        mn.z = fminf(mn.z, v.z); mn.w = fminf(mn.w, v.w);
        mx.x = fmaxf(mx.x, v.x); mx.y = fmaxf(mx.y, v.y);
        mx.z = fmaxf(mx.z, v.z); mx.w = fmaxf(mx.w, v.w);
    }
    size_t o = (size_t)blockIdx.y * NCOLS + c;
    *(float4*)(pmin + o) = mn;
    *(float4*)(pmax + o) = mx;
}

// Reduce 64 partials per column; emit fmin, safe_range, 1/safe_range.
__global__ __launch_bounds__(256) void finalize_part(const float* __restrict__ pmin,
                                                     const float* __restrict__ pmax,
                                                     float* __restrict__ fmin,
                                                     float* __restrict__ fsr,
                                                     float* __restrict__ finv) {
    int col = blockIdx.x * 256 + threadIdx.x;
    float mn = pmin[col];
    float mx = pmax[col];
#pragma unroll 9
    for (int y = 1; y < NTILES; ++y) {
        mn = fminf(mn, pmin[(size_t)y * NCOLS + col]);
        mx = fmaxf(mx, pmax[(size_t)y * NCOLS + col]);
    }
    float r = mx - mn;
    float sr = (r == 0.0f) ? 1.0f : r;  // sklearn _handle_zeros_in_scale
    fmin[col] = mn;
    fsr[col] = sr;
    finv[col] = 1.0f / sr;
}

// ===================== rowiter ============================================

// One-barrier block sum: double-buffered slots; consecutive calls alternate
// slot, so a slot's next writer is separated from its readers by a barrier.
__device__ __forceinline__ float block_sum(float v, float* red, int slot) {
#pragma unroll
    for (int m = 32; m; m >>= 1) v += __shfl_xor(v, m, 64);
    int wid = threadIdx.x >> 6;
    int lane = threadIdx.x & 63;
    if (lane == 0) red[slot * 4 + wid] = v;
    __syncthreads();
    float* r = red + slot * 4;
    return (r[0] + r[1]) + (r[2] + r[3]);
}

// One block per row; 8 x float4/thread in registers (32 data VGPRs).
// __launch_bounds__(256, 8): 8 blocks/CU -> 2048 concurrent slots; 4096
// blocks = exactly 2 scheduling rounds (no tail quantization) and deep
// inter-block load/compute/store overlap. 3 VALU/elem inner loop; final
// iteration fused with denormalize + non-temporal stores.
__global__ __launch_bounds__(256, 8) void rowiter(const float* __restrict__ x,
                                                  const float* __restrict__ fmin,
                                                  const float* __restrict__ fsr,
                                                  const float* __restrict__ finv,
                                                  float* __restrict__ out) {
    int row = blockIdx.x;
    int t = threadIdx.x;
    const float* xr = x + (size_t)row * NCOLS;
    float* outr = out + (size_t)row * NCOLS;

    __shared__ float red[8];

    float4 a[8];
    float psum = 0.0f;
#pragma unroll
    for (int k = 0; k < 8; ++k) {
        int c = k * 1024 + t * 4;
        float4 v = *(const float4*)(xr + c);
        float4 mn = *(const float4*)(fmin + c);
        float4 iv = *(const float4*)(finv + c);
        float4 u;
        u.x = (v.x - mn.x) * iv.x;
        u.y = (v.y - mn.y) * iv.y;
        u.z = (v.z - mn.z) * iv.z;
        u.w = (v.w - mn.w) * iv.w;
        a[k] = u;
        psum += (u.x + u.y) + (u.z + u.w);
    }
    float sum = block_sum(psum, red, 0);

    // iterations 0..8 (iteration 9 fused below); 3 VALU/elem
#pragma unroll
    for (int it = 0; it < 9; ++it) {
        float c1 = 1.0f + sum * (1.0f / 8192.0f);  // 1 + mean (exact pow-2 div)
        float add = (it == 0) ? 0.001f : 0.0f;
        psum = 0.0f;
#pragma unroll
        for (int k = 0; k < 8; ++k) {
            float4 u = a[k];
            u.x = fmaf(u.x, c1 - u.x, add);
            u.y = fmaf(u.y, c1 - u.y, add);
            u.z = fmaf(u.z, c1 - u.z, add);
            u.w = fmaf(u.w, c1 - u.w, add);
            a[k] = u;
            psum += (u.x + u.y) + (u.z + u.w);
        }
        sum = block_sum(psum, red, (it + 1) & 1);
    }

    // iteration 9 fused with denormalize + non-temporal store
    {
        float c1 = 1.0f + sum * (1.0f / 8192.0f);
#pragma unroll
        for (int k = 0; k < 8; ++k) {
            int c = k * 1024 + t * 4;
            float4 mn = *(const float4*)(fmin + c);
            float4 sr = *(const float4*)(fsr + c);
            float4 u = a[k];
            u.x = u.x * (c1 - u.x);
            u.y = u.y * (c1 - u.y);
            u.z = u.z * (c1 - u.z);
            u.w = u.w * (c1 - u.w);
            float* o = outr + c;
            __builtin_nontemporal_store(fmaf(u.x, sr.x, mn.x), o + 0);
            __builtin_nontemporal_store(fmaf(u.y, sr.y, mn.y), o + 1);
            __builtin_nontemporal_store(fmaf(u.z, sr.z, mn.z), o + 2);
            __builtin_nontemporal_store(fmaf(u.w, sr.w, mn.w), o + 3);
        }
    }
}

extern "C" void kernel_launch(void* const* d_in, const int* in_sizes, int n_in,
                              void* d_out, int out_size, void* d_ws, size_t ws_size,
                              hipStream_t stream) {
    const float* x = (const float*)d_in[0];
    float* out = (float*)d_out;

    // ws layout: pmin[64][8192] f32 (2 MiB) | pmax (2 MiB) |
    //            fmin | fsr | finv (32 KiB each)  = 4.09 MiB
    float* pmin = (float*)d_ws;
    float* pmax = pmin + (size_t)NTILES * NCOLS;
    float* fmin = pmax + (size_t)NTILES * NCOLS;
    float* fsr = fmin + NCOLS;
    float* finv = fsr + NCOLS;

    colminmax_part<<<dim3(NCOLS / 1024, NTILES), 256, 0, stream>>>(x, pmin, pmax);
    finalize_part<<<NCOLS / 256, 256, 0, stream>>>(pmin, pmax, fmin, fsr, finv);
    rowiter<<<DROWS, 256, 0, stream>>>(x, fmin, fsr, finv, out);
}

// Round 14
// 73.483 us; speedup vs baseline: 1.7053x; 1.0377x over previous
//
#include <hip/hip_runtime.h>

#define DROWS 4096
#define NCOLS 8192
#define RTILE 64                 // rows per colminmax tile
#define NTILES (DROWS / RTILE)   // 64 partial tiles

typedef float v2f __attribute__((ext_vector_type(2)));

// ===================== two-level column min/max ===========================

// Per-column partial min/max over a 64-row tile. grid (8, 64); block 256 thr,
// 4 cols/thread, coalesced float4. No atomics, no init required.
__global__ __launch_bounds__(256) void colminmax_part(const float* __restrict__ x,
                                                      float* __restrict__ pmin,
                                                      float* __restrict__ pmax) {
    int c = blockIdx.x * 1024 + threadIdx.x * 4;
    int r0 = blockIdx.y * RTILE;
    const float* p = x + (size_t)r0 * NCOLS + c;

    float4 mn = *(const float4*)p;
    float4 mx = mn;
#pragma unroll 8
    for (int i = 1; i < RTILE; ++i) {
        float4 v = *(const float4*)(p + (size_t)i * NCOLS);
        mn.x = fminf(mn.x, v.x); mn.y = fminf(mn.y, v.y);
        mn.z = fminf(mn.z, v.z); mn.w = fminf(mn.w, v.w);
        mx.x = fmaxf(mx.x, v.x); mx.y = fmaxf(mx.y, v.y);
        mx.z = fmaxf(mx.z, v.z); mx.w = fmaxf(mx.w, v.w);
    }
    size_t o = (size_t)blockIdx.y * NCOLS + c;
    *(float4*)(pmin + o) = mn;
    *(float4*)(pmax + o) = mx;
}

// Reduce 64 partials per column; emit fmin, safe_range, 1/safe_range.
__global__ __launch_bounds__(256) void finalize_part(const float* __restrict__ pmin,
                                                     const float* __restrict__ pmax,
                                                     float* __restrict__ fmin,
                                                     float* __restrict__ fsr,
                                                     float* __restrict__ finv) {
    int col = blockIdx.x * 256 + threadIdx.x;
    float mn = pmin[col];
    float mx = pmax[col];
#pragma unroll 9
    for (int y = 1; y < NTILES; ++y) {
        mn = fminf(mn, pmin[(size_t)y * NCOLS + col]);
        mx = fmaxf(mx, pmax[(size_t)y * NCOLS + col]);
    }
    float r = mx - mn;
    float sr = (r == 0.0f) ? 1.0f : r;  // sklearn _handle_zeros_in_scale
    fmin[col] = mn;
    fsr[col] = sr;
    finv[col] = 1.0f / sr;
}

// ===================== rowiter ============================================

// One-barrier block sum: double-buffered slots; consecutive calls alternate
// slot, so a slot's next writer is separated from its readers by a barrier.
__device__ __forceinline__ float block_sum(float v, float* red, int slot) {
#pragma unroll
    for (int m = 32; m; m >>= 1) v += __shfl_xor(v, m, 64);
    int wid = threadIdx.x >> 6;
    int lane = threadIdx.x & 63;
    if (lane == 0) red[slot * 4 + wid] = v;
    __syncthreads();
    float* r = red + slot * 4;
    return (r[0] + r[1]) + (r[2] + r[3]);
}

// One block per row; row data as 16 x v2f per thread (32 data VGPRs).
// Iteration loop uses packed fp32 (v_pk_fma_f32 / v_pk_add_f32): ~1.5
// VALU ops/elem instead of 3, shrinking the compute window between the
// load and store phases. Final iteration fused with NT-store epilogue.
__global__ __launch_bounds__(256, 6) void rowiter(const float* __restrict__ x,
                                                  const float* __restrict__ fmin,
                                                  const float* __restrict__ fsr,
                                                  const float* __restrict__ finv,
                                                  float* __restrict__ out) {
    int row = blockIdx.x;
    int t = threadIdx.x;
    const float* xr = x + (size_t)row * NCOLS;
    float* outr = out + (size_t)row * NCOLS;

    __shared__ float red[8];

    v2f a[16];
    float psum = 0.0f;
#pragma unroll
    for (int k = 0; k < 8; ++k) {
        int c = k * 1024 + t * 4;
        float4 v = *(const float4*)(xr + c);
        float4 mn = *(const float4*)(fmin + c);
        float4 iv = *(const float4*)(finv + c);
        float4 u;
        u.x = (v.x - mn.x) * iv.x;
        u.y = (v.y - mn.y) * iv.y;
        u.z = (v.z - mn.z) * iv.z;
        u.w = (v.w - mn.w) * iv.w;
        a[2 * k] = v2f{u.x, u.y};
        a[2 * k + 1] = v2f{u.z, u.w};
        psum += (u.x + u.y) + (u.z + u.w);
    }
    float sum = block_sum(psum, red, 0);

    // iterations 0..8 (iteration 9 fused below); packed fp32
#pragma unroll
    for (int it = 0; it < 9; ++it) {
        float c1 = 1.0f + sum * (1.0f / 8192.0f);  // 1 + mean (exact pow-2 div)
        float add = (it == 0) ? 0.001f : 0.0f;
        v2f c1v = {c1, c1};
        v2f addv = {add, add};
        v2f ps = {0.0f, 0.0f};
#pragma unroll
        for (int k = 0; k < 16; ++k) {
            v2f u = a[k];
            u = __builtin_elementwise_fma(u, c1v - u, addv);  // v_pk_fma_f32
            a[k] = u;
            ps += u;                                           // v_pk_add_f32
        }
        sum = block_sum(ps.x + ps.y, red, (it + 1) & 1);
    }

    // iteration 9 fused with denormalize + non-temporal store
    {
        float c1 = 1.0f + sum * (1.0f / 8192.0f);
        v2f c1v = {c1, c1};
#pragma unroll
        for (int k = 0; k < 8; ++k) {
            int c = k * 1024 + t * 4;
            float4 mn = *(const float4*)(fmin + c);
            float4 sr = *(const float4*)(fsr + c);
            v2f lo = a[2 * k], hi = a[2 * k + 1];
            lo = lo * (c1v - lo);   // v_pk_mul / v_pk_add
            hi = hi * (c1v - hi);
            float* o = outr + c;
            __builtin_nontemporal_store(fmaf(lo.x, sr.x, mn.x), o + 0);
            __builtin_nontemporal_store(fmaf(lo.y, sr.y, mn.y), o + 1);
            __builtin_nontemporal_store(fmaf(hi.x, sr.z, mn.z), o + 2);
            __builtin_nontemporal_store(fmaf(hi.y, sr.w, mn.w), o + 3);
        }
    }
}

extern "C" void kernel_launch(void* const* d_in, const int* in_sizes, int n_in,
                              void* d_out, int out_size, void* d_ws, size_t ws_size,
                              hipStream_t stream) {
    const float* x = (const float*)d_in[0];
    float* out = (float*)d_out;

    // ws layout: pmin[64][8192] f32 (2 MiB) | pmax (2 MiB) |
    //            fmin | fsr | finv (32 KiB each)  = 4.09 MiB
    float* pmin = (float*)d_ws;
    float* pmax = pmin + (size_t)NTILES * NCOLS;
    float* fmin = pmax + (size_t)NTILES * NCOLS;
    float* fsr = fmin + NCOLS;
    float* finv = fsr + NCOLS;

    colminmax_part<<<dim3(NCOLS / 1024, NTILES), 256, 0, stream>>>(x, pmin, pmax);
    finalize_part<<<NCOLS / 256, 256, 0, stream>>>(pmin, pmax, fmin, fsr, finv);
    rowiter<<<DROWS, 256, 0, stream>>>(x, fmin, fsr, finv, out);
}